// Round 1
// baseline (762.452 us; speedup 1.0000x reference)
//
#include <hip/hip_runtime.h>
#include <hip/hip_bf16.h>
#include <cstdint>
#include <cstddef>

typedef __bf16 bf16_t;
typedef __attribute__((ext_vector_type(8))) __bf16 bf16x8;
typedef __attribute__((ext_vector_type(4))) __bf16 bf16x4;
typedef __attribute__((ext_vector_type(4))) float f32x4;

#define DEVI static __device__ __forceinline__

DEVI void gload_lds16(const void* g, void* l) {
    __builtin_amdgcn_global_load_lds((const __attribute__((address_space(1))) void*)g,
                                     (__attribute__((address_space(3))) void*)l, 16, 0, 0);
}

// ---------------------------------------------------------------------------
// Weight transpose + cast: W (K x N, f32, row-major) -> Wt (N x K, bf16)
// ---------------------------------------------------------------------------
__global__ __launch_bounds__(256)
void transpose_cast_kernel(const float* __restrict__ W, bf16_t* __restrict__ Wt,
                           int K, int N) {
    int idx = blockIdx.x * 256 + threadIdx.x;   // index over Wt (N*K)
    if (idx >= N * K) return;
    int n = idx / K;
    int k = idx - n * K;
    Wt[idx] = (bf16_t)W[(size_t)k * N + n];
}

// ---------------------------------------------------------------------------
// GEMM: C[M,N] = act(A[M,K] @ B[K,N] + bias), B given as Bt[N,K] bf16.
// 128x128 tile, 4 waves (2x2), BK=64, mfma_f32_16x16x32_bf16.
// AF32: A is f32 with leading dim lda (converted to bf16 during staging).
// OUTF32: C written as f32 (no relu), else bf16 with relu per RELU flag.
// ---------------------------------------------------------------------------
template<int AF32, int RELU, int OUTF32>
__global__ __launch_bounds__(256)
void gemm_kernel(const void* __restrict__ Ap, const bf16_t* __restrict__ Bt,
                 const float* __restrict__ bias, void* __restrict__ Cp,
                 int M, int N, int K, int lda) {
    __shared__ __align__(16) bf16_t Asm[128 * 64];
    __shared__ __align__(16) bf16_t Bsm[128 * 64];

    const int t  = threadIdx.x;
    const int bn = blockIdx.x;
    const int bm = blockIdx.y;
    const int l  = t & 63;
    const int w  = t >> 6;
    const int wm = w >> 1;     // 0..1
    const int wn = w & 1;      // 0..1

    f32x4 acc[4][4];
    const f32x4 zero = {0.f, 0.f, 0.f, 0.f};
#pragma unroll
    for (int m = 0; m < 4; ++m)
#pragma unroll
        for (int n = 0; n < 4; ++n) acc[m][n] = zero;

    const bf16_t* Ab = (const bf16_t*)Ap;
    const float*  Af = (const float*)Ap;

    for (int k0 = 0; k0 < K; k0 += 64) {
        // ---- stage A tile (128 rows x 64 k) into Asm ----
        if (AF32) {
            // f32 source: load float4, convert, ds_write_b64
#pragma unroll
            for (int i = 0; i < 8; ++i) {
                int e = i * 1024 + t * 4;          // element offset in tile
                int r = e >> 6, c = e & 63;
                const float4 v = *(const float4*)(Af + (size_t)(bm * 128 + r) * lda + k0 + c);
                bf16x4 pv;
                pv[0] = (bf16_t)v.x; pv[1] = (bf16_t)v.y;
                pv[2] = (bf16_t)v.z; pv[3] = (bf16_t)v.w;
                *(bf16x4*)(Asm + e) = pv;
            }
        } else {
#pragma unroll
            for (int i = 0; i < 4; ++i) {
                int e = i * 2048 + t * 8;
                int r = e >> 6, c = e & 63;
                gload_lds16(Ab + (size_t)(bm * 128 + r) * lda + k0 + c, Asm + e);
            }
        }
        // ---- stage B tile: Bt rows bn*128..+128, cols k0..+64 ----
#pragma unroll
        for (int i = 0; i < 4; ++i) {
            int e = i * 2048 + t * 8;
            int r = e >> 6, c = e & 63;
            gload_lds16(Bt + (size_t)(bn * 128 + r) * K + k0 + c, Bsm + e);
        }
        __syncthreads();

        const int lr = l & 15;
        const int lk = (l >> 4) << 3;
#pragma unroll
        for (int ks = 0; ks < 2; ++ks) {
            bf16x8 af[4], bfr[4];
#pragma unroll
            for (int m = 0; m < 4; ++m)
                af[m] = *(const bf16x8*)(Asm + (wm * 64 + m * 16 + lr) * 64 + ks * 32 + lk);
#pragma unroll
            for (int n = 0; n < 4; ++n)
                bfr[n] = *(const bf16x8*)(Bsm + (wn * 64 + n * 16 + lr) * 64 + ks * 32 + lk);
#pragma unroll
            for (int m = 0; m < 4; ++m)
#pragma unroll
                for (int n = 0; n < 4; ++n)
                    acc[m][n] = __builtin_amdgcn_mfma_f32_16x16x32_bf16(af[m], bfr[n], acc[m][n], 0, 0, 0);
        }
        __syncthreads();
    }

    // ---- epilogue ----
    float bv[4];
#pragma unroll
    for (int n = 0; n < 4; ++n) bv[n] = bias[bn * 128 + wn * 64 + n * 16 + (l & 15)];

    const int row0 = bm * 128 + wm * 64 + ((l >> 4) << 2);
    const int col0 = bn * 128 + wn * 64 + (l & 15);
#pragma unroll
    for (int m = 0; m < 4; ++m) {
#pragma unroll
        for (int n = 0; n < 4; ++n) {
#pragma unroll
            for (int r = 0; r < 4; ++r) {
                float v = acc[m][n][r] + bv[n];
                if (RELU) v = fmaxf(v, 0.f);
                size_t idx = (size_t)(row0 + m * 16 + r) * N + (col0 + n * 16);
                if (OUTF32) ((float*)Cp)[idx] = v;
                else        ((bf16_t*)Cp)[idx] = (bf16_t)v;
            }
        }
    }
}

// ---------------------------------------------------------------------------
// Finisher: identity copy, affine coupling, logabsdet row-reduction.
// One wave per row (4 rows per 256-thread block).
// ---------------------------------------------------------------------------
__global__ __launch_bounds__(256)
void finish_kernel(const float* __restrict__ x, const float* __restrict__ params,
                   float* __restrict__ out, float* __restrict__ lad) {
    const int row = blockIdx.x * 4 + (threadIdx.x >> 6);
    const int l   = threadIdx.x & 63;
    const float* xr = x + (size_t)row * 512;
    const float* pr = params + (size_t)row * 512;
    float* orow = out + (size_t)row * 512;

    // identity half: copy through
    float4 idv = *(const float4*)(xr + l * 4);
    *(float4*)(orow + l * 4) = idv;

    float4 xt = *(const float4*)(xr + 256 + l * 4);
    float4 sh = *(const float4*)(pr + l * 4);
    float4 us = *(const float4*)(pr + 256 + l * 4);

    float s0 = 1.f / (1.f + expf(-(us.x + 2.f))) + 0.001f;
    float s1 = 1.f / (1.f + expf(-(us.y + 2.f))) + 0.001f;
    float s2 = 1.f / (1.f + expf(-(us.z + 2.f))) + 0.001f;
    float s3 = 1.f / (1.f + expf(-(us.w + 2.f))) + 0.001f;

    float4 tr;
    tr.x = xt.x * s0 + sh.x;
    tr.y = xt.y * s1 + sh.y;
    tr.z = xt.z * s2 + sh.z;
    tr.w = xt.w * s3 + sh.w;
    *(float4*)(orow + 256 + l * 4) = tr;

    float ls = logf(s0) + logf(s1) + logf(s2) + logf(s3);
#pragma unroll
    for (int off = 32; off; off >>= 1) ls += __shfl_xor(ls, off);
    if (l == 0) lad[row] = ls;
}

// ---------------------------------------------------------------------------
extern "C" void kernel_launch(void* const* d_in, const int* in_sizes, int n_in,
                              void* d_out, int out_size, void* d_ws, size_t ws_size,
                              hipStream_t stream) {
    const int B = 65536, D = 512, D_ID = 256, H = 1024, NP = 512; // NP = 2*D_TR

    const float* x  = (const float*)d_in[0];
    const float* W1 = (const float*)d_in[1];
    const float* b1 = (const float*)d_in[2];
    const float* W2 = (const float*)d_in[3];
    const float* b2 = (const float*)d_in[4];
    const float* W3 = (const float*)d_in[5];
    const float* b3 = (const float*)d_in[6];
    const float* W4 = (const float*)d_in[7];
    const float* b4 = (const float*)d_in[8];

    float* out = (float*)d_out;
    float* lad = out + (size_t)B * D;

    char* ws = (char*)d_ws;
    const size_t hbytes = (size_t)B * H * sizeof(bf16_t);      // 128 MiB
    bf16_t* hA     = (bf16_t*)ws;
    bf16_t* hB     = (bf16_t*)(ws + hbytes);
    float*  params = (float*) (ws + hbytes);                   // aliases hB (free by then)
    bf16_t* W1t    = (bf16_t*)(ws + 2 * hbytes);
    bf16_t* W2t    = W1t + (size_t)H * D_ID;
    bf16_t* W3t    = W2t + (size_t)H * H;
    bf16_t* W4t    = W3t + (size_t)H * H;

    dim3 blk(256);
    // weight transposes (f32 -> bf16, [K][N] -> [N][K])
    transpose_cast_kernel<<<dim3((H * D_ID + 255) / 256), blk, 0, stream>>>(W1, W1t, D_ID, H);
    transpose_cast_kernel<<<dim3((H * H + 255) / 256),    blk, 0, stream>>>(W2, W2t, H, H);
    transpose_cast_kernel<<<dim3((H * H + 255) / 256),    blk, 0, stream>>>(W3, W3t, H, H);
    transpose_cast_kernel<<<dim3((H * NP + 255) / 256),   blk, 0, stream>>>(W4, W4t, H, NP);

    dim3 gh(H / 128, B / 128);     // (8, 512)
    dim3 gp(NP / 128, B / 128);    // (4, 512)

    // layer 1: A = x (f32, lda=512, first 256 cols), relu, bf16 out
    gemm_kernel<1, 1, 0><<<gh, blk, 0, stream>>>(x,  W1t, b1, hA, B, H, D_ID, D);
    // layer 2
    gemm_kernel<0, 1, 0><<<gh, blk, 0, stream>>>(hA, W2t, b2, hB, B, H, H, H);
    // layer 3
    gemm_kernel<0, 1, 0><<<gh, blk, 0, stream>>>(hB, W3t, b3, hA, B, H, H, H);
    // layer 4: params (f32, no relu)
    gemm_kernel<0, 0, 1><<<gp, blk, 0, stream>>>(hA, W4t, b4, params, B, NP, H, H);

    // coupling epilogue + logabsdet
    finish_kernel<<<dim3(B / 4), blk, 0, stream>>>(x, params, out, lad);
}

// Round 2
// 745.163 us; speedup vs baseline: 1.0232x; 1.0232x over previous
//
#include <hip/hip_runtime.h>
#include <hip/hip_bf16.h>
#include <cstdint>
#include <cstddef>

typedef __bf16 bf16_t;
typedef __attribute__((ext_vector_type(8))) __bf16 bf16x8;
typedef __attribute__((ext_vector_type(4))) __bf16 bf16x4;
typedef __attribute__((ext_vector_type(4))) float f32x4;

#define DEVI static __device__ __forceinline__

DEVI void gload_lds16(const void* g, void* l) {
    __builtin_amdgcn_global_load_lds((const __attribute__((address_space(1))) void*)g,
                                     (__attribute__((address_space(3))) void*)l, 16, 0, 0);
}

// XCD-band block mapping: 1-D grid; xcd = lin&7 owns a disjoint contiguous
// band of M-tiles; within a band, bn varies fastest so blocks sharing an
// A-panel are co-resident on one XCD's L2.
DEVI void xcd_map(int lin, int nblk, int gx, int& bm, int& bn) {
    int xcd  = lin & 7;
    int slot = lin >> 3;
    int mper = (nblk / gx) >> 3;      // M-tiles per XCD band
    bm = xcd * mper + slot / gx;
    bn = slot % gx;
}

// ---------------------------------------------------------------------------
// Weight transpose + cast: W (K x N, f32, row-major) -> Wt (N x K, bf16)
// ---------------------------------------------------------------------------
__global__ __launch_bounds__(256)
void transpose_cast_kernel(const float* __restrict__ W, bf16_t* __restrict__ Wt,
                           int K, int N) {
    int idx = blockIdx.x * 256 + threadIdx.x;
    if (idx >= N * K) return;
    int n = idx / K;
    int k = idx - n * K;
    Wt[idx] = (bf16_t)W[(size_t)k * N + n];
}

// ---------------------------------------------------------------------------
// GEMM: C[M,N] = act(A[M,K] @ B[K,N] + bias), B given as Bt[N,K] bf16.
// 128x128 tile, 4 waves (2x2), BK=64, mfma_f32_16x16x32_bf16.
// ---------------------------------------------------------------------------
template<int AF32, int RELU, int OUTF32>
__global__ __launch_bounds__(256)
void gemm_kernel(const void* __restrict__ Ap, const bf16_t* __restrict__ Bt,
                 const float* __restrict__ bias, void* __restrict__ Cp,
                 int N, int K, int lda, int gx) {
    __shared__ __align__(16) bf16_t Asm[128 * 64];
    __shared__ __align__(16) bf16_t Bsm[128 * 64];

    const int t = threadIdx.x;
    int bm, bn;
    xcd_map(blockIdx.x, gridDim.x, gx, bm, bn);
    const int l  = t & 63;
    const int w  = t >> 6;
    const int wm = w >> 1;
    const int wn = w & 1;

    f32x4 acc[4][4];
    const f32x4 zero = {0.f, 0.f, 0.f, 0.f};
#pragma unroll
    for (int m = 0; m < 4; ++m)
#pragma unroll
        for (int n = 0; n < 4; ++n) acc[m][n] = zero;

    const bf16_t* Ab = (const bf16_t*)Ap;
    const float*  Af = (const float*)Ap;

    for (int k0 = 0; k0 < K; k0 += 64) {
        if (AF32) {
#pragma unroll
            for (int i = 0; i < 8; ++i) {
                int e = i * 1024 + t * 4;
                int r = e >> 6, c = e & 63;
                const float4 v = *(const float4*)(Af + (size_t)(bm * 128 + r) * lda + k0 + c);
                bf16x4 pv;
                pv[0] = (bf16_t)v.x; pv[1] = (bf16_t)v.y;
                pv[2] = (bf16_t)v.z; pv[3] = (bf16_t)v.w;
                *(bf16x4*)(Asm + e) = pv;
            }
        } else {
#pragma unroll
            for (int i = 0; i < 4; ++i) {
                int e = i * 2048 + t * 8;
                int r = e >> 6, c = e & 63;
                gload_lds16(Ab + (size_t)(bm * 128 + r) * lda + k0 + c, Asm + e);
            }
        }
#pragma unroll
        for (int i = 0; i < 4; ++i) {
            int e = i * 2048 + t * 8;
            int r = e >> 6, c = e & 63;
            gload_lds16(Bt + (size_t)(bn * 128 + r) * K + k0 + c, Bsm + e);
        }
        __syncthreads();

        const int lr = l & 15;
        const int lk = (l >> 4) << 3;
#pragma unroll
        for (int ks = 0; ks < 2; ++ks) {
            bf16x8 af[4], bfr[4];
#pragma unroll
            for (int m = 0; m < 4; ++m)
                af[m] = *(const bf16x8*)(Asm + (wm * 64 + m * 16 + lr) * 64 + ks * 32 + lk);
#pragma unroll
            for (int n = 0; n < 4; ++n)
                bfr[n] = *(const bf16x8*)(Bsm + (wn * 64 + n * 16 + lr) * 64 + ks * 32 + lk);
#pragma unroll
            for (int m = 0; m < 4; ++m)
#pragma unroll
                for (int n = 0; n < 4; ++n)
                    acc[m][n] = __builtin_amdgcn_mfma_f32_16x16x32_bf16(af[m], bfr[n], acc[m][n], 0, 0, 0);
        }
        __syncthreads();
    }

    float bv[4];
#pragma unroll
    for (int n = 0; n < 4; ++n) bv[n] = bias[bn * 128 + wn * 64 + n * 16 + (l & 15)];

    const int row0 = bm * 128 + wm * 64 + ((l >> 4) << 2);
    const int col0 = bn * 128 + wn * 64 + (l & 15);
#pragma unroll
    for (int m = 0; m < 4; ++m) {
#pragma unroll
        for (int n = 0; n < 4; ++n) {
#pragma unroll
            for (int r = 0; r < 4; ++r) {
                float v = acc[m][n][r] + bv[n];
                if (RELU) v = fmaxf(v, 0.f);
                size_t idx = (size_t)(row0 + m * 16 + r) * N + (col0 + n * 16);
                if (OUTF32) ((float*)Cp)[idx] = v;
                else        ((bf16_t*)Cp)[idx] = (bf16_t)v;
            }
        }
    }
}

// ---------------------------------------------------------------------------
// Fused layer 4 + coupling epilogue.
// Block (bm, bn): rows bm*128..+128, transform cols bn*128..+128 (of 256).
// Computes BOTH the shift tile (W4 cols bn*128..) and the scale tile
// (W4 cols 256+bn*128..); applies sigmoid/affine/log; writes out directly;
// also copies the identity half and emits logabsdet partials.
// ---------------------------------------------------------------------------
__global__ __launch_bounds__(256)
void gemm4_fused_kernel(const bf16_t* __restrict__ A, const bf16_t* __restrict__ W4t,
                        const float* __restrict__ b4, const float* __restrict__ x,
                        float* __restrict__ out, float* __restrict__ part) {
    const int B = 65536, K = 1024, D = 512;
    __shared__ __align__(16) bf16_t Asm[128 * 64];
    __shared__ __align__(16) bf16_t Bsm[2][128 * 64];

    const int t = threadIdx.x;
    int bm, bn;
    xcd_map(blockIdx.x, gridDim.x, 2, bm, bn);
    const int l  = t & 63;
    const int w  = t >> 6;
    const int wm = w >> 1;
    const int wn = w & 1;

    f32x4 acc[2][4][4];
    const f32x4 zero = {0.f, 0.f, 0.f, 0.f};
#pragma unroll
    for (int h = 0; h < 2; ++h)
#pragma unroll
        for (int m = 0; m < 4; ++m)
#pragma unroll
            for (int n = 0; n < 4; ++n) acc[h][m][n] = zero;

    for (int k0 = 0; k0 < K; k0 += 64) {
#pragma unroll
        for (int i = 0; i < 4; ++i) {
            int e = i * 2048 + t * 8;
            int r = e >> 6, c = e & 63;
            gload_lds16(A + (size_t)(bm * 128 + r) * K + k0 + c, Asm + e);
        }
#pragma unroll
        for (int h = 0; h < 2; ++h)
#pragma unroll
            for (int i = 0; i < 4; ++i) {
                int e = i * 2048 + t * 8;
                int r = e >> 6, c = e & 63;
                gload_lds16(W4t + (size_t)(h * 256 + bn * 128 + r) * K + k0 + c, Bsm[h] + e);
            }
        __syncthreads();

        const int lr = l & 15;
        const int lk = (l >> 4) << 3;
#pragma unroll
        for (int ks = 0; ks < 2; ++ks) {
            bf16x8 af[4], bfr[2][4];
#pragma unroll
            for (int m = 0; m < 4; ++m)
                af[m] = *(const bf16x8*)(Asm + (wm * 64 + m * 16 + lr) * 64 + ks * 32 + lk);
#pragma unroll
            for (int h = 0; h < 2; ++h)
#pragma unroll
                for (int n = 0; n < 4; ++n)
                    bfr[h][n] = *(const bf16x8*)(Bsm[h] + (wn * 64 + n * 16 + lr) * 64 + ks * 32 + lk);
#pragma unroll
            for (int h = 0; h < 2; ++h)
#pragma unroll
                for (int m = 0; m < 4; ++m)
#pragma unroll
                    for (int n = 0; n < 4; ++n)
                        acc[h][m][n] = __builtin_amdgcn_mfma_f32_16x16x32_bf16(af[m], bfr[h][n], acc[h][m][n], 0, 0, 0);
        }
        __syncthreads();
    }

    // identity half copy: x[rows, bn*128..+128] -> out (float4, coalesced)
#pragma unroll
    for (int i = 0; i < 16; ++i) {
        int e = i * 256 + t;              // float4 index within 128x32 grid
        int r = e >> 5, c4 = e & 31;
        const float4 v = *(const float4*)(x + (size_t)(bm * 128 + r) * D + bn * 128 + c4 * 4);
        *(float4*)(out + (size_t)(bm * 128 + r) * D + bn * 128 + c4 * 4) = v;
    }

    const int lr = l & 15;
    float bvs[4], bvu[4];
#pragma unroll
    for (int n = 0; n < 4; ++n) {
        bvs[n] = b4[bn * 128 + wn * 64 + n * 16 + lr];
        bvu[n] = b4[256 + bn * 128 + wn * 64 + n * 16 + lr];
    }

    const int row0 = bm * 128 + wm * 64 + ((l >> 4) << 2);
    const int ct0  = bn * 128 + wn * 64 + lr;      // transform col (0..255)
    float lsum[4][4];                               // per (m,r) log-scale partial
#pragma unroll
    for (int m = 0; m < 4; ++m)
#pragma unroll
        for (int r = 0; r < 4; ++r) lsum[m][r] = 0.f;

#pragma unroll
    for (int m = 0; m < 4; ++m) {
#pragma unroll
        for (int n = 0; n < 4; ++n) {
#pragma unroll
            for (int r = 0; r < 4; ++r) {
                int row = row0 + m * 16 + r;
                int ct  = ct0 + n * 16;
                float shift = acc[0][m][n][r] + bvs[n];
                float u     = acc[1][m][n][r] + bvu[n];
                float s  = 1.f / (1.f + __expf(-(u + 2.f))) + 0.001f;
                float xv = x[(size_t)row * D + 256 + ct];
                out[(size_t)row * D + 256 + ct] = xv * s + shift;
                lsum[m][r] += __logf(s);
            }
        }
    }
    // reduce log-scale partials across the 16 lanes sharing each row
#pragma unroll
    for (int m = 0; m < 4; ++m)
#pragma unroll
        for (int r = 0; r < 4; ++r) {
#pragma unroll
            for (int off = 8; off; off >>= 1) lsum[m][r] += __shfl_xor(lsum[m][r], off);
        }
    if (lr == 0) {
        const size_t pbase = (size_t)(bn * 2 + wn) * B;
#pragma unroll
        for (int m = 0; m < 4; ++m)
#pragma unroll
            for (int r = 0; r < 4; ++r)
                part[pbase + row0 + m * 16 + r] = lsum[m][r];
    }
}

__global__ __launch_bounds__(256)
void lad_reduce_kernel(const float* __restrict__ part, float* __restrict__ lad) {
    const int B = 65536;
    int r = blockIdx.x * 256 + threadIdx.x;
    lad[r] = part[r] + part[B + r] + part[2 * (size_t)B + r] + part[3 * (size_t)B + r];
}

// ---------------------------------------------------------------------------
extern "C" void kernel_launch(void* const* d_in, const int* in_sizes, int n_in,
                              void* d_out, int out_size, void* d_ws, size_t ws_size,
                              hipStream_t stream) {
    const int B = 65536, D = 512, D_ID = 256, H = 1024, NP = 512;

    const float* x  = (const float*)d_in[0];
    const float* W1 = (const float*)d_in[1];
    const float* b1 = (const float*)d_in[2];
    const float* W2 = (const float*)d_in[3];
    const float* b2 = (const float*)d_in[4];
    const float* W3 = (const float*)d_in[5];
    const float* b3 = (const float*)d_in[6];
    const float* W4 = (const float*)d_in[7];
    const float* b4 = (const float*)d_in[8];

    float* out = (float*)d_out;
    float* lad = out + (size_t)B * D;

    char* ws = (char*)d_ws;
    const size_t hbytes = (size_t)B * H * sizeof(bf16_t);      // 128 MiB
    bf16_t* hA   = (bf16_t*)ws;
    bf16_t* hB   = (bf16_t*)(ws + hbytes);
    float*  part = (float*) (ws + hbytes);                     // aliases hB (free by L4)
    bf16_t* W1t  = (bf16_t*)(ws + 2 * hbytes);
    bf16_t* W2t  = W1t + (size_t)H * D_ID;
    bf16_t* W3t  = W2t + (size_t)H * H;
    bf16_t* W4t  = W3t + (size_t)H * H;

    dim3 blk(256);
    transpose_cast_kernel<<<dim3((H * D_ID + 255) / 256), blk, 0, stream>>>(W1, W1t, D_ID, H);
    transpose_cast_kernel<<<dim3((H * H + 255) / 256),    blk, 0, stream>>>(W2, W2t, H, H);
    transpose_cast_kernel<<<dim3((H * H + 255) / 256),    blk, 0, stream>>>(W3, W3t, H, H);
    transpose_cast_kernel<<<dim3((H * NP + 255) / 256),   blk, 0, stream>>>(W4, W4t, H, NP);

    const int nblk_h = (B / 128) * (H / 128);     // 4096

    // layer 1: A = x (f32, lda=512, first 256 cols), relu, bf16 out
    gemm_kernel<1, 1, 0><<<dim3(nblk_h), blk, 0, stream>>>(x,  W1t, b1, hA, H, D_ID, D, H / 128);
    // layer 2
    gemm_kernel<0, 1, 0><<<dim3(nblk_h), blk, 0, stream>>>(hA, W2t, b2, hB, H, H, H, H / 128);
    // layer 3
    gemm_kernel<0, 1, 0><<<dim3(nblk_h), blk, 0, stream>>>(hB, W3t, b3, hA, H, H, H, H / 128);
    // layer 4 fused with coupling epilogue (grid: 512 M-tiles x 2 N-tiles)
    gemm4_fused_kernel<<<dim3((B / 128) * 2), blk, 0, stream>>>(hA, W4t, b4, x, out, part);
    // logabsdet final reduce
    lad_reduce_kernel<<<dim3(B / 256), blk, 0, stream>>>(part, lad);
}

// Round 3
// 521.818 us; speedup vs baseline: 1.4611x; 1.4280x over previous
//
#include <hip/hip_runtime.h>
#include <hip/hip_bf16.h>
#include <cstdint>
#include <cstddef>

typedef __bf16 bf16_t;
typedef __attribute__((ext_vector_type(8))) __bf16 bf16x8;
typedef __attribute__((ext_vector_type(4))) float f32x4;

#define DEVI static __device__ __forceinline__

DEVI void gload_lds16(const void* g, void* l) {
    __builtin_amdgcn_global_load_lds((const __attribute__((address_space(1))) void*)g,
                                     (__attribute__((address_space(3))) void*)l, 16, 0, 0);
}

#define BARR() __builtin_amdgcn_s_barrier()
#define LGKM0() do { asm volatile("s_waitcnt lgkmcnt(0)" ::: "memory"); \
                     __builtin_amdgcn_sched_barrier(0); } while (0)
#define SCHED0() __builtin_amdgcn_sched_barrier(0)
#define VMW5() asm volatile("s_waitcnt vmcnt(5)" ::: "memory")
#define VMW0() asm volatile("s_waitcnt vmcnt(0)" ::: "memory")
#define SP(x) __builtin_amdgcn_s_setprio(x)

// XCD-band mapping: xcd = lin&7 owns a contiguous M-band; bn fastest within.
DEVI void xcd_map(int lin, int nblk, int gx, int& bm, int& bn) {
    int xcd  = lin & 7;
    int slot = lin >> 3;
    int mper = (nblk / gx) >> 3;
    bm = xcd * mper + slot / gx;
    bn = slot % gx;
}

// ---------------------------------------------------------------------------
__global__ __launch_bounds__(256)
void transpose_cast_kernel(const float* __restrict__ W, bf16_t* __restrict__ Wt,
                           int K, int N) {
    int idx = blockIdx.x * 256 + threadIdx.x;
    if (idx >= N * K) return;
    int n = idx / K;
    int k = idx - n * K;
    Wt[idx] = (bf16_t)W[(size_t)k * N + n];
}

// cast x[:, :256] f32 -> bf16 (A operand of layer 1)
__global__ __launch_bounds__(256)
void cast_x_kernel(const float* __restrict__ x, bf16_t* __restrict__ xb) {
    int g = blockIdx.x * 256 + threadIdx.x;     // over B*32
    int row = g >> 5, c8 = (g & 31) * 8;
    const float4 v0 = *(const float4*)(x + (size_t)row * 512 + c8);
    const float4 v1 = *(const float4*)(x + (size_t)row * 512 + c8 + 4);
    bf16x8 o;
    o[0] = (bf16_t)v0.x; o[1] = (bf16_t)v0.y; o[2] = (bf16_t)v0.z; o[3] = (bf16_t)v0.w;
    o[4] = (bf16_t)v1.x; o[5] = (bf16_t)v1.y; o[6] = (bf16_t)v1.z; o[7] = (bf16_t)v1.w;
    *(bf16x8*)(xb + (size_t)row * 256 + c8) = o;
}

// ---------------------------------------------------------------------------
// 8-phase 256x256 GEMM (BK=64, 8 waves 2Mx4N, dbuf LDS 128 KiB, swizzled).
// A[M,K] bf16 row-major; Bt[N,K] bf16 row-major; C = act(A @ Bt^T + bias).
// LDS layout per buffer p: A planes [kk][256 rows][32 k] (16KB each),
// B planes [kk][rho=nq*128+wn*32+..][32 k]; 16B-chunk swizzle: chunk ^= (row>>1)&3.
// ---------------------------------------------------------------------------
#define LOAD_A(P, KK) do { \
    const char* _s = lds + (P) * 65536 + (KK) * 16384; \
    _Pragma("unroll") \
    for (int m = 0; m < 8; ++m) af[m] = *(const bf16x8*)(_s + aOff[m]); \
} while (0)

#define LOAD_B(P, KK, NQ) do { \
    const char* _s = lds + (P) * 65536 + 32768 + (KK) * 16384; \
    bf[0] = *(const bf16x8*)(_s + bOff[(NQ)][0]); \
    bf[1] = *(const bf16x8*)(_s + bOff[(NQ)][1]); \
} while (0)

#define MFMA16(NQ) do { \
    _Pragma("unroll") \
    for (int m = 0; m < 8; ++m) { \
        acc[m][(NQ)*2+0] = __builtin_amdgcn_mfma_f32_16x16x32_bf16(af[m], bf[0], acc[m][(NQ)*2+0], 0, 0, 0); \
        acc[m][(NQ)*2+1] = __builtin_amdgcn_mfma_f32_16x16x32_bf16(af[m], bf[1], acc[m][(NQ)*2+1], 0, 0, 0); \
    } \
} while (0)

template<int RELU, int OUTF32>
__global__ __launch_bounds__(512, 2)
void gemm8_kernel(const bf16_t* __restrict__ A, const bf16_t* __restrict__ Bt,
                  const float* __restrict__ bias, void* __restrict__ Cp,
                  int N, int K, int NI, int gx) {
    __shared__ __align__(16) char lds[131072];

    const int tid = threadIdx.x;
    int bm, bn; xcd_map(blockIdx.x, gridDim.x, gx, bm, bn);
    const int rowBase = bm * 256, colBase = bn * 256;
    const int l  = tid & 63;
    const int w  = tid >> 6;
    const int wm = w >> 2, wn = w & 3;
    const int lr = l & 15, lq = l >> 4;
    const int qa = lq ^ ((lr >> 1) & 3);          // swizzled chunk for reads

    int aOff[8];
#pragma unroll
    for (int m = 0; m < 8; ++m) aOff[m] = (wm * 128 + m * 16 + lr) * 64 + qa * 16;
    int bOff[2][2];
#pragma unroll
    for (int nq = 0; nq < 2; ++nq)
#pragma unroll
        for (int nf = 0; nf < 2; ++nf)
            bOff[nq][nf] = (nq * 128 + wn * 32 + nf * 16 + lr) * 64 + qa * 16;

    // staging coords (pre-swizzled source)
    const int ca8 = ((tid & 3) ^ ((tid >> 3) & 3)) * 8;   // swizzled k-chunk * 8
    const int sar = tid >> 2;                             // A row (+ h*128)
    const int sbr = ((tid >> 7) & 3) * 64 + ((tid >> 2) & 31);  // B row (+ nq*32)

    auto STAGE_A = [&](int t, int kk) {      // one A k-half plane (2 issues)
        char* dst = lds + (t & 1) * 65536 + kk * 16384;
#pragma unroll
        for (int h = 0; h < 2; ++h)
            gload_lds16(A + (size_t)(rowBase + h * 128 + sar) * K + t * 64 + kk * 32 + ca8,
                        dst + h * 8192 + tid * 16);
    };
    auto STAGE_B = [&](int t, int kk, int nq) {   // one B (nq,kk) band (1 issue)
        char* dst = lds + (t & 1) * 65536 + 32768 + kk * 16384 + nq * 8192;
        gload_lds16(Bt + (size_t)(colBase + sbr + nq * 32) * K + t * 64 + kk * 32 + ca8,
                    dst + tid * 16);
    };

    f32x4 acc[8][4];
    const f32x4 zero = {0.f, 0.f, 0.f, 0.f};
#pragma unroll
    for (int m = 0; m < 8; ++m)
#pragma unroll
        for (int n = 0; n < 4; ++n) acc[m][n] = zero;
    bf16x8 af[8], bf[2];

    // ---- prologue: t0 fully, t1 all but (Akh1,B11); leave 5 in flight ----
    STAGE_B(0, 0, 0); STAGE_A(0, 0); STAGE_B(0, 0, 1); STAGE_B(0, 1, 0);
    STAGE_A(0, 1);    STAGE_B(0, 1, 1);
    STAGE_B(1, 0, 0); STAGE_A(1, 0); STAGE_B(1, 0, 1); STAGE_B(1, 1, 0);
    VMW5(); BARR();

    for (int i = 0; i < NI - 1; ++i) {
        const int tb = 2 * i + 1, tc = 2 * i + 2, td = 2 * i + 3;
        // P1: ta (kk0,nq0); stage Akh1+B11 of tb
        LOAD_A(0, 0); LOAD_B(0, 0, 0); STAGE_A(tb, 1); STAGE_B(tb, 1, 1);
        SCHED0(); BARR(); LGKM0();
        SP(1); MFMA16(0); SP(0); SCHED0(); BARR();
        // P2: (kk0,nq1); stage B00(tc)
        LOAD_B(0, 0, 1); STAGE_B(tc, 0, 0);
        SCHED0(); BARR(); LGKM0();
        SP(1); MFMA16(1); SP(0); SCHED0(); BARR();
        // P3: (kk1,nq0); stage Akh0(tc)
        LOAD_A(0, 1); LOAD_B(0, 1, 0); STAGE_A(tc, 0);
        SCHED0(); BARR(); LGKM0();
        SP(1); MFMA16(0); SP(0); SCHED0(); BARR();
        // P4: (kk1,nq1); stage B10(tc)+B01(tc); counted wait
        LOAD_B(0, 1, 1); STAGE_B(tc, 0, 1); STAGE_B(tc, 1, 0);
        SCHED0(); BARR(); LGKM0();
        SP(1); MFMA16(1); SP(0); VMW5(); SCHED0(); BARR();
        // P5: tb (kk0,nq0); stage Akh1+B11 of tc
        LOAD_A(1, 0); LOAD_B(1, 0, 0); STAGE_A(tc, 1); STAGE_B(tc, 1, 1);
        SCHED0(); BARR(); LGKM0();
        SP(1); MFMA16(0); SP(0); SCHED0(); BARR();
        // P6: (kk0,nq1); stage B00(td)
        LOAD_B(1, 0, 1); STAGE_B(td, 0, 0);
        SCHED0(); BARR(); LGKM0();
        SP(1); MFMA16(1); SP(0); SCHED0(); BARR();
        // P7: (kk1,nq0); stage Akh0(td)
        LOAD_A(1, 1); LOAD_B(1, 1, 0); STAGE_A(td, 0);
        SCHED0(); BARR(); LGKM0();
        SP(1); MFMA16(0); SP(0); SCHED0(); BARR();
        // P8: (kk1,nq1); stage B10(td)+B01(td); counted wait
        LOAD_B(1, 1, 1); STAGE_B(td, 0, 1); STAGE_B(td, 1, 0);
        SCHED0(); BARR(); LGKM0();
        SP(1); MFMA16(1); SP(0); VMW5(); SCHED0(); BARR();
    }
    // ---- final iteration: tiles 2(NI-1), 2(NI-1)+1; drain ----
    {
        const int tb = 2 * (NI - 1) + 1;
        LOAD_A(0, 0); LOAD_B(0, 0, 0); STAGE_A(tb, 1); STAGE_B(tb, 1, 1);
        SCHED0(); BARR(); LGKM0();
        SP(1); MFMA16(0); SP(0); SCHED0(); BARR();
        LOAD_B(0, 0, 1);
        SCHED0(); BARR(); LGKM0();
        SP(1); MFMA16(1); SP(0); SCHED0(); BARR();
        LOAD_A(0, 1); LOAD_B(0, 1, 0);
        SCHED0(); BARR(); LGKM0();
        SP(1); MFMA16(0); SP(0); SCHED0(); BARR();
        LOAD_B(0, 1, 1);
        SCHED0(); BARR(); LGKM0();
        SP(1); MFMA16(1); SP(0); VMW0(); SCHED0(); BARR();
        LOAD_A(1, 0); LOAD_B(1, 0, 0);
        SCHED0(); BARR(); LGKM0();
        SP(1); MFMA16(0); SP(0); SCHED0(); BARR();
        LOAD_B(1, 0, 1);
        SCHED0(); BARR(); LGKM0();
        SP(1); MFMA16(1); SP(0); SCHED0(); BARR();
        LOAD_A(1, 1); LOAD_B(1, 1, 0);
        SCHED0(); BARR(); LGKM0();
        SP(1); MFMA16(0); SP(0); SCHED0(); BARR();
        LOAD_B(1, 1, 1);
        SCHED0(); BARR(); LGKM0();
        SP(1); MFMA16(1); SP(0);
    }

    // ---- epilogue ----
    float bv[4];
#pragma unroll
    for (int n = 0; n < 4; ++n) bv[n] = bias[colBase + wn * 64 + n * 16 + lr];
    const int row0 = rowBase + wm * 128 + lq * 4;
    const int col0 = colBase + wn * 64 + lr;
#pragma unroll
    for (int m = 0; m < 8; ++m)
#pragma unroll
        for (int n = 0; n < 4; ++n)
#pragma unroll
            for (int r = 0; r < 4; ++r) {
                float v = acc[m][n][r] + bv[n];
                if (RELU) v = fmaxf(v, 0.f);
                size_t idx = (size_t)(row0 + m * 16 + r) * N + (col0 + n * 16);
                if (OUTF32) ((float*)Cp)[idx] = v;
                else        ((bf16_t*)Cp)[idx] = (bf16_t)v;
            }
}

// ---------------------------------------------------------------------------
// Coupling finisher: identity copy, affine transform, logabsdet (1 wave/row).
// ---------------------------------------------------------------------------
__global__ __launch_bounds__(256)
void finish_kernel(const float* __restrict__ x, const float* __restrict__ params,
                   float* __restrict__ out, float* __restrict__ lad) {
    const int row = blockIdx.x * 4 + (threadIdx.x >> 6);
    const int l   = threadIdx.x & 63;
    const float* xr = x + (size_t)row * 512;
    const float* pr = params + (size_t)row * 512;
    float* orow = out + (size_t)row * 512;

    float4 idv = *(const float4*)(xr + l * 4);
    *(float4*)(orow + l * 4) = idv;

    float4 xt = *(const float4*)(xr + 256 + l * 4);
    float4 sh = *(const float4*)(pr + l * 4);
    float4 us = *(const float4*)(pr + 256 + l * 4);

    float s0 = 1.f / (1.f + expf(-(us.x + 2.f))) + 0.001f;
    float s1 = 1.f / (1.f + expf(-(us.y + 2.f))) + 0.001f;
    float s2 = 1.f / (1.f + expf(-(us.z + 2.f))) + 0.001f;
    float s3 = 1.f / (1.f + expf(-(us.w + 2.f))) + 0.001f;

    float4 tr;
    tr.x = xt.x * s0 + sh.x;
    tr.y = xt.y * s1 + sh.y;
    tr.z = xt.z * s2 + sh.z;
    tr.w = xt.w * s3 + sh.w;
    *(float4*)(orow + 256 + l * 4) = tr;

    float ls = logf(s0) + logf(s1) + logf(s2) + logf(s3);
#pragma unroll
    for (int off = 32; off; off >>= 1) ls += __shfl_xor(ls, off);
    if (l == 0) lad[row] = ls;
}

// ---------------------------------------------------------------------------
extern "C" void kernel_launch(void* const* d_in, const int* in_sizes, int n_in,
                              void* d_out, int out_size, void* d_ws, size_t ws_size,
                              hipStream_t stream) {
    const int B = 65536, D_ID = 256, H = 1024, NP = 512;

    const float* x  = (const float*)d_in[0];
    const float* W1 = (const float*)d_in[1];
    const float* b1 = (const float*)d_in[2];
    const float* W2 = (const float*)d_in[3];
    const float* b2 = (const float*)d_in[4];
    const float* W3 = (const float*)d_in[5];
    const float* b3 = (const float*)d_in[6];
    const float* W4 = (const float*)d_in[7];
    const float* b4 = (const float*)d_in[8];

    float* out = (float*)d_out;
    float* lad = out + (size_t)B * 512;

    char* ws = (char*)d_ws;
    const size_t hbytes = (size_t)B * H * sizeof(bf16_t);      // 128 MiB
    bf16_t* hA     = (bf16_t*)ws;
    bf16_t* hB     = (bf16_t*)(ws + hbytes);
    bf16_t* xb     = (bf16_t*)(ws + hbytes);                   // alias hB (dead before L2)
    float*  params = (float*) (ws + hbytes);                   // alias hB (dead after L3)
    bf16_t* W1t    = (bf16_t*)(ws + 2 * hbytes);
    bf16_t* W2t    = W1t + (size_t)H * D_ID;
    bf16_t* W3t    = W2t + (size_t)H * H;
    bf16_t* W4t    = W3t + (size_t)H * H;

    dim3 blk(256), blk8(512);
    cast_x_kernel<<<dim3(B * 32 / 256), blk, 0, stream>>>(x, xb);
    transpose_cast_kernel<<<dim3((H * D_ID + 255) / 256), blk, 0, stream>>>(W1, W1t, D_ID, H);
    transpose_cast_kernel<<<dim3((H * H + 255) / 256),    blk, 0, stream>>>(W2, W2t, H, H);
    transpose_cast_kernel<<<dim3((H * H + 255) / 256),    blk, 0, stream>>>(W3, W3t, H, H);
    transpose_cast_kernel<<<dim3((H * NP + 255) / 256),   blk, 0, stream>>>(W4, W4t, H, NP);

    const int gridH = (B / 256) * (H / 256);    // 1024
    const int gridP = (B / 256) * (NP / 256);   // 512

    // layer 1: K=256 (NI=2)
    gemm8_kernel<1, 0><<<dim3(gridH), blk8, 0, stream>>>(xb, W1t, b1, hA, H, D_ID, D_ID / 128, H / 256);
    // layer 2,3: K=1024 (NI=8)
    gemm8_kernel<1, 0><<<dim3(gridH), blk8, 0, stream>>>(hA, W2t, b2, hB, H, H, H / 128, H / 256);
    gemm8_kernel<1, 0><<<dim3(gridH), blk8, 0, stream>>>(hB, W3t, b3, hA, H, H, H / 128, H / 256);
    // layer 4: N=512, f32 out
    gemm8_kernel<0, 1><<<dim3(gridP), blk8, 0, stream>>>(hA, W4t, b4, params, NP, H, H / 128, NP / 256);

    finish_kernel<<<dim3(B / 4), blk, 0, stream>>>(x, params, out, lad);
}

// Round 4
// 497.150 us; speedup vs baseline: 1.5336x; 1.0496x over previous
//
#include <hip/hip_runtime.h>
#include <hip/hip_bf16.h>
#include <cstdint>
#include <cstddef>

typedef __bf16 bf16_t;
typedef __attribute__((ext_vector_type(8))) __bf16 bf16x8;
typedef __attribute__((ext_vector_type(4))) __bf16 bf16x4;
typedef __attribute__((ext_vector_type(4))) float f32x4;

#define DEVI static __device__ __forceinline__

DEVI void gload_lds16(const void* g, void* l) {
    __builtin_amdgcn_global_load_lds((const __attribute__((address_space(1))) void*)g,
                                     (__attribute__((address_space(3))) void*)l, 16, 0, 0);
}

#define BARR() __builtin_amdgcn_s_barrier()
#define LGKM0() do { asm volatile("s_waitcnt lgkmcnt(0)" ::: "memory"); \
                     __builtin_amdgcn_sched_barrier(0); } while (0)
#define SCHED0() __builtin_amdgcn_sched_barrier(0)
#define VMW(n) asm volatile("s_waitcnt vmcnt(" #n ")" ::: "memory")
#define SP(x) __builtin_amdgcn_s_setprio(x)

// XCD-band mapping: xcd = lin&7 owns a contiguous M-band; bn fastest within.
DEVI void xcd_map(int lin, int nblk, int gx, int& bm, int& bn) {
    int xcd  = lin & 7;
    int slot = lin >> 3;
    int mper = (nblk / gx) >> 3;
    bm = xcd * mper + slot / gx;
    bn = slot % gx;
}

// ---------------------------------------------------------------------------
__global__ __launch_bounds__(256)
void transpose_cast_kernel(const float* __restrict__ W, bf16_t* __restrict__ Wt,
                           int K, int N) {
    int idx = blockIdx.x * 256 + threadIdx.x;
    if (idx >= N * K) return;
    int n = idx / K;
    int k = idx - n * K;
    Wt[idx] = (bf16_t)W[(size_t)k * N + n];
}

// cast x[:, :256] f32 -> bf16 (A operand of layer 1)
__global__ __launch_bounds__(256)
void cast_x_kernel(const float* __restrict__ x, bf16_t* __restrict__ xb) {
    int g = blockIdx.x * 256 + threadIdx.x;     // over B*32
    int row = g >> 5, c8 = (g & 31) * 8;
    const float4 v0 = *(const float4*)(x + (size_t)row * 512 + c8);
    const float4 v1 = *(const float4*)(x + (size_t)row * 512 + c8 + 4);
    bf16x8 o;
    o[0] = (bf16_t)v0.x; o[1] = (bf16_t)v0.y; o[2] = (bf16_t)v0.z; o[3] = (bf16_t)v0.w;
    o[4] = (bf16_t)v1.x; o[5] = (bf16_t)v1.y; o[6] = (bf16_t)v1.z; o[7] = (bf16_t)v1.w;
    *(bf16x8*)(xb + (size_t)row * 256 + c8) = o;
}

// W4 column-permuted transpose: W4p[vt][k]; within N-tile bn, virtual col
// v = v16*16 + c: v16 even -> shift col (bn*128 + (v16>>1)*16 + c),
//                 v16 odd  -> scale col (256 + same). Bias likewise.
__global__ __launch_bounds__(256)
void permute_w4_kernel(const float* __restrict__ W4, bf16_t* __restrict__ W4p,
                       const float* __restrict__ b4, float* __restrict__ b4p) {
    int idx = blockIdx.x * 256 + threadIdx.x;   // over 512*1024
    int vt = idx >> 10, k = idx & 1023;
    int bn = vt >> 8, v = vt & 255;
    int v16 = v >> 4, c = v & 15;
    int tcol = bn * 128 + (v16 >> 1) * 16 + c;
    int col = (v16 & 1) ? 256 + tcol : tcol;
    W4p[idx] = (bf16_t)W4[(size_t)k * 512 + col];
    if (k == 0) b4p[vt] = b4[col];
}

// ---------------------------------------------------------------------------
// 8-phase 256x256 GEMM (BK=64, 8 waves 2Mx4N, dbuf LDS 128 KiB, swizzled).
// Swapped-operand MFMA: acc holds C^T-layout fragments -> reg index walks
// 4 consecutive COLUMNS -> vectorized epilogue stores.
// MODE 0: relu + bf16 out. MODE 2: fused coupling epilogue (f32 out, x, part).
// SMALLK: K=256 fully-staged counted-vmcnt path (no mid drain).
// ---------------------------------------------------------------------------
#define LOAD_A(P, KK) do { \
    const char* _s = lds + (P) * 65536 + (KK) * 16384; \
    _Pragma("unroll") \
    for (int m = 0; m < 8; ++m) af[m] = *(const bf16x8*)(_s + aOff[m]); \
} while (0)

#define LOAD_B(P, KK, NQ) do { \
    const char* _s = lds + (P) * 65536 + 32768 + (KK) * 16384; \
    bfr[0] = *(const bf16x8*)(_s + bOff[(NQ)][0]); \
    bfr[1] = *(const bf16x8*)(_s + bOff[(NQ)][1]); \
} while (0)

#define MFMA16(NQ) do { \
    _Pragma("unroll") \
    for (int m = 0; m < 8; ++m) { \
        acc[m][(NQ)*2+0] = __builtin_amdgcn_mfma_f32_16x16x32_bf16(bfr[0], af[m], acc[m][(NQ)*2+0], 0, 0, 0); \
        acc[m][(NQ)*2+1] = __builtin_amdgcn_mfma_f32_16x16x32_bf16(bfr[1], af[m], acc[m][(NQ)*2+1], 0, 0, 0); \
    } \
} while (0)

template<int MODE, int SMALLK>
__global__ __launch_bounds__(512, 2)
void gemm8_kernel(const bf16_t* __restrict__ A, const bf16_t* __restrict__ Bt,
                  const float* __restrict__ bias, void* __restrict__ Cp,
                  const float* __restrict__ x, float* __restrict__ part,
                  int N, int K, int NI, int gx) {
    __shared__ __align__(16) char lds[131072];

    const int tid = threadIdx.x;
    int bm, bn; xcd_map(blockIdx.x, gridDim.x, gx, bm, bn);
    const int rowBase = bm * 256, colBase = bn * 256;
    const int l  = tid & 63;
    const int w  = tid >> 6;
    const int wm = w >> 2, wn = w & 3;
    const int lr = l & 15, lq = l >> 4;
    const int qa = lq ^ ((lr >> 1) & 3);          // swizzled chunk for reads

    int aOff[8];
#pragma unroll
    for (int m = 0; m < 8; ++m) aOff[m] = (wm * 128 + m * 16 + lr) * 64 + qa * 16;
    int bOff[2][2];
#pragma unroll
    for (int nq = 0; nq < 2; ++nq)
#pragma unroll
        for (int nf = 0; nf < 2; ++nf)
            bOff[nq][nf] = (nq * 128 + wn * 32 + nf * 16 + lr) * 64 + qa * 16;

    // staging coords (pre-swizzled source)
    const int ca8 = ((tid & 3) ^ ((tid >> 3) & 3)) * 8;
    const int sar = tid >> 2;
    const int sbr = ((tid >> 7) & 3) * 64 + ((tid >> 2) & 31);

    auto STAGE_A = [&](int t, int kk) {      // one A k-half plane (2 issues)
        char* dst = lds + (t & 1) * 65536 + kk * 16384;
#pragma unroll
        for (int h = 0; h < 2; ++h)
            gload_lds16(A + (size_t)(rowBase + h * 128 + sar) * K + t * 64 + kk * 32 + ca8,
                        dst + h * 8192 + tid * 16);
    };
    auto STAGE_B = [&](int t, int kk, int nq) {   // one B (nq,kk) band (1 issue)
        char* dst = lds + (t & 1) * 65536 + 32768 + kk * 16384 + nq * 8192;
        gload_lds16(Bt + (size_t)(colBase + sbr + nq * 32) * K + t * 64 + kk * 32 + ca8,
                    dst + tid * 16);
    };

    f32x4 acc[8][4];
    const f32x4 zero = {0.f, 0.f, 0.f, 0.f};
#pragma unroll
    for (int m = 0; m < 8; ++m)
#pragma unroll
        for (int n = 0; n < 4; ++n) acc[m][n] = zero;
    bf16x8 af[8], bfr[2];

    if (SMALLK) {
        // ---- K=256: stage both tiles fully; counted waits, no drain ----
        STAGE_B(0, 0, 0); STAGE_A(0, 0); STAGE_B(0, 0, 1);
        STAGE_B(0, 1, 0); STAGE_A(0, 1); STAGE_B(0, 1, 1);
        STAGE_B(1, 0, 0); STAGE_A(1, 0); STAGE_B(1, 0, 1);
        STAGE_B(1, 1, 0); STAGE_A(1, 1); STAGE_B(1, 1, 1);
        VMW(13); BARR(); LOAD_A(0, 0); LOAD_B(0, 0, 0); LGKM0();
        SP(1); MFMA16(0); SP(0); SCHED0();
        VMW(12); BARR(); LOAD_B(0, 0, 1); LGKM0();
        SP(1); MFMA16(1); SP(0); SCHED0();
        VMW(9);  BARR(); LOAD_A(0, 1); LOAD_B(0, 1, 0); LGKM0();
        SP(1); MFMA16(0); SP(0); SCHED0();
        VMW(8);  BARR(); LOAD_B(0, 1, 1); LGKM0();
        SP(1); MFMA16(1); SP(0); SCHED0();
        VMW(5);  BARR(); LOAD_A(1, 0); LOAD_B(1, 0, 0); LGKM0();
        SP(1); MFMA16(0); SP(0); SCHED0();
        VMW(4);  BARR(); LOAD_B(1, 0, 1); LGKM0();
        SP(1); MFMA16(1); SP(0); SCHED0();
        VMW(1);  BARR(); LOAD_A(1, 1); LOAD_B(1, 1, 0); LGKM0();
        SP(1); MFMA16(0); SP(0); SCHED0();
        VMW(0);  BARR(); LOAD_B(1, 1, 1); LGKM0();
        SP(1); MFMA16(1); SP(0); SCHED0();
    } else {
        // ---- prologue: t0 fully, t1 all but (Akh1,B11); 5 left in flight ----
        STAGE_B(0, 0, 0); STAGE_A(0, 0); STAGE_B(0, 0, 1); STAGE_B(0, 1, 0);
        STAGE_A(0, 1);    STAGE_B(0, 1, 1);
        STAGE_B(1, 0, 0); STAGE_A(1, 0); STAGE_B(1, 0, 1); STAGE_B(1, 1, 0);
        VMW(5); BARR();

        for (int i = 0; i < NI - 1; ++i) {
            const int tb = 2 * i + 1, tc = 2 * i + 2, td = 2 * i + 3;
            LOAD_A(0, 0); LOAD_B(0, 0, 0); STAGE_A(tb, 1); STAGE_B(tb, 1, 1);
            SCHED0(); BARR(); LGKM0();
            SP(1); MFMA16(0); SP(0); SCHED0(); BARR();
            LOAD_B(0, 0, 1); STAGE_B(tc, 0, 0);
            SCHED0(); BARR(); LGKM0();
            SP(1); MFMA16(1); SP(0); SCHED0(); BARR();
            LOAD_A(0, 1); LOAD_B(0, 1, 0); STAGE_A(tc, 0);
            SCHED0(); BARR(); LGKM0();
            SP(1); MFMA16(0); SP(0); SCHED0(); BARR();
            LOAD_B(0, 1, 1); STAGE_B(tc, 0, 1); STAGE_B(tc, 1, 0);
            SCHED0(); BARR(); LGKM0();
            SP(1); MFMA16(1); SP(0); VMW(5); SCHED0(); BARR();
            LOAD_A(1, 0); LOAD_B(1, 0, 0); STAGE_A(tc, 1); STAGE_B(tc, 1, 1);
            SCHED0(); BARR(); LGKM0();
            SP(1); MFMA16(0); SP(0); SCHED0(); BARR();
            LOAD_B(1, 0, 1); STAGE_B(td, 0, 0);
            SCHED0(); BARR(); LGKM0();
            SP(1); MFMA16(1); SP(0); SCHED0(); BARR();
            LOAD_A(1, 1); LOAD_B(1, 1, 0); STAGE_A(td, 0);
            SCHED0(); BARR(); LGKM0();
            SP(1); MFMA16(0); SP(0); SCHED0(); BARR();
            LOAD_B(1, 1, 1); STAGE_B(td, 0, 1); STAGE_B(td, 1, 0);
            SCHED0(); BARR(); LGKM0();
            SP(1); MFMA16(1); SP(0); VMW(5); SCHED0(); BARR();
        }
        {
            const int tb = 2 * (NI - 1) + 1;
            LOAD_A(0, 0); LOAD_B(0, 0, 0); STAGE_A(tb, 1); STAGE_B(tb, 1, 1);
            SCHED0(); BARR(); LGKM0();
            SP(1); MFMA16(0); SP(0); SCHED0(); BARR();
            LOAD_B(0, 0, 1);
            SCHED0(); BARR(); LGKM0();
            SP(1); MFMA16(1); SP(0); SCHED0(); BARR();
            LOAD_A(0, 1); LOAD_B(0, 1, 0);
            SCHED0(); BARR(); LGKM0();
            SP(1); MFMA16(0); SP(0); SCHED0(); BARR();
            LOAD_B(0, 1, 1);
            SCHED0(); BARR(); LGKM0();
            SP(1); MFMA16(1); SP(0); VMW(0); SCHED0(); BARR();
            LOAD_A(1, 0); LOAD_B(1, 0, 0);
            SCHED0(); BARR(); LGKM0();
            SP(1); MFMA16(0); SP(0); SCHED0(); BARR();
            LOAD_B(1, 0, 1);
            SCHED0(); BARR(); LGKM0();
            SP(1); MFMA16(1); SP(0); SCHED0(); BARR();
            LOAD_A(1, 1); LOAD_B(1, 1, 0);
            SCHED0(); BARR(); LGKM0();
            SP(1); MFMA16(0); SP(0); SCHED0(); BARR();
            LOAD_B(1, 1, 1);
            SCHED0(); BARR(); LGKM0();
            SP(1); MFMA16(1); SP(0);
        }
    }

    // ---- epilogue (C^T fragment layout: lane lr = row, lq*4+r = col) ----
    float4 bv[4];
#pragma unroll
    for (int n = 0; n < 4; ++n)
        bv[n] = *(const float4*)(bias + colBase + wn * 64 + n * 16 + lq * 4);
    const int row0 = rowBase + wm * 128;

    if (MODE == 0) {
        bf16_t* C = (bf16_t*)Cp;
#pragma unroll
        for (int m = 0; m < 8; ++m) {
            const int row = row0 + m * 16 + lr;
#pragma unroll
            for (int n = 0; n < 4; ++n) {
                bf16x4 pv;
#pragma unroll
                for (int r = 0; r < 4; ++r) {
                    float v = acc[m][n][r] + ((const float*)&bv[n])[r];
                    pv[r] = (bf16_t)fmaxf(v, 0.f);
                }
                *(bf16x4*)(C + (size_t)row * N + colBase + wn * 64 + n * 16 + lq * 4) = pv;
            }
        }
    } else {
        const int B = 65536;
        float* out = (float*)Cp;
        // identity copy: this block's 128 identity cols for its 256 rows
#pragma unroll
        for (int i = 0; i < 16; ++i) {
            int idx = i * 512 + tid;
            int rr = idx >> 5, c4 = idx & 31;
            *(float4*)(out + (size_t)(rowBase + rr) * 512 + bn * 128 + c4 * 4) =
                *(const float4*)(x + (size_t)(rowBase + rr) * 512 + bn * 128 + c4 * 4);
        }
#pragma unroll
        for (int m = 0; m < 8; ++m) {
            const int row = row0 + m * 16 + lr;
            float lsum = 0.f;
#pragma unroll
            for (int p = 0; p < 2; ++p) {
                const int tcol = bn * 128 + wn * 32 + p * 16 + lq * 4;
                const float4 xt = *(const float4*)(x + (size_t)row * 512 + 256 + tcol);
                float4 ov;
#pragma unroll
                for (int r = 0; r < 4; ++r) {
                    float sh = acc[m][2 * p][r]     + ((const float*)&bv[2 * p])[r];
                    float u  = acc[m][2 * p + 1][r] + ((const float*)&bv[2 * p + 1])[r];
                    float s  = 1.f / (1.f + __expf(-(u + 2.f))) + 0.001f;
                    ((float*)&ov)[r] = ((const float*)&xt)[r] * s + sh;
                    lsum += __logf(s);
                }
                *(float4*)(out + (size_t)row * 512 + 256 + tcol) = ov;
            }
            lsum += __shfl_xor(lsum, 16);
            lsum += __shfl_xor(lsum, 32);
            if (lq == 0) part[(size_t)(bn * 4 + wn) * B + row] = lsum;
        }
    }
}

__global__ __launch_bounds__(256)
void lad_reduce_kernel(const float* __restrict__ part, float* __restrict__ lad) {
    const int B = 65536;
    int rIdx = blockIdx.x * 256 + threadIdx.x;
    float s = 0.f;
#pragma unroll
    for (int j = 0; j < 8; ++j) s += part[(size_t)j * B + rIdx];
    lad[rIdx] = s;
}

// ---------------------------------------------------------------------------
extern "C" void kernel_launch(void* const* d_in, const int* in_sizes, int n_in,
                              void* d_out, int out_size, void* d_ws, size_t ws_size,
                              hipStream_t stream) {
    const int B = 65536, D_ID = 256, H = 1024, NP = 512;

    const float* x  = (const float*)d_in[0];
    const float* W1 = (const float*)d_in[1];
    const float* b1 = (const float*)d_in[2];
    const float* W2 = (const float*)d_in[3];
    const float* b2 = (const float*)d_in[4];
    const float* W3 = (const float*)d_in[5];
    const float* b3 = (const float*)d_in[6];
    const float* W4 = (const float*)d_in[7];
    const float* b4 = (const float*)d_in[8];

    float* out = (float*)d_out;
    float* lad = out + (size_t)B * 512;

    char* ws = (char*)d_ws;
    const size_t hbytes = (size_t)B * H * sizeof(bf16_t);      // 128 MiB
    bf16_t* hA   = (bf16_t*)ws;
    bf16_t* hB   = (bf16_t*)(ws + hbytes);
    bf16_t* xb   = (bf16_t*)(ws + hbytes);                     // alias hB (dead before L2)
    float*  part = (float*) (ws + hbytes);                     // alias hB (dead after L3)
    bf16_t* W1t  = (bf16_t*)(ws + 2 * hbytes);
    bf16_t* W2t  = W1t + (size_t)H * D_ID;
    bf16_t* W3t  = W2t + (size_t)H * H;
    bf16_t* W4p  = W3t + (size_t)H * H;
    float*  b4p  = (float*)(W4p + (size_t)NP * H);

    dim3 blk(256), blk8(512);
    cast_x_kernel<<<dim3(B * 32 / 256), blk, 0, stream>>>(x, xb);
    transpose_cast_kernel<<<dim3((H * D_ID + 255) / 256), blk, 0, stream>>>(W1, W1t, D_ID, H);
    transpose_cast_kernel<<<dim3((H * H + 255) / 256),    blk, 0, stream>>>(W2, W2t, H, H);
    transpose_cast_kernel<<<dim3((H * H + 255) / 256),    blk, 0, stream>>>(W3, W3t, H, H);
    permute_w4_kernel<<<dim3(NP * H / 256), blk, 0, stream>>>(W4, W4p, b4, b4p);

    const int gridH = (B / 256) * (H / 256);    // 1024
    const int gridP = (B / 256) * (NP / 256);   // 512

    // layer 1: K=256, fully-staged small-K path
    gemm8_kernel<0, 1><<<dim3(gridH), blk8, 0, stream>>>(xb, W1t, b1, hA, nullptr, nullptr, H, D_ID, 2, H / 256);
    // layers 2,3: K=1024 (NI=8)
    gemm8_kernel<0, 0><<<dim3(gridH), blk8, 0, stream>>>(hA, W2t, b2, hB, nullptr, nullptr, H, H, H / 128, H / 256);
    gemm8_kernel<0, 0><<<dim3(gridH), blk8, 0, stream>>>(hB, W3t, b3, hA, nullptr, nullptr, H, H, H / 128, H / 256);
    // layer 4 fused with coupling epilogue (f32 out written directly)
    gemm8_kernel<2, 0><<<dim3(gridP), blk8, 0, stream>>>(hA, W4p, b4p, out, x, part, NP, H, H / 128, NP / 256);

    lad_reduce_kernel<<<dim3(B / 256), blk, 0, stream>>>(part, lad);
}